// Round 8
// baseline (258.488 us; speedup 1.0000x reference)
//
#include <hip/hip_runtime.h>
#include <cstddef>

#define EPSF 1e-6f

constexpr int D   = 1024;
constexpr int Bv  = 2;
constexpr int S   = 2048;
constexpr int M   = Bv * S;    // 4096
constexpr int CH  = 256;       // chunk
constexpr int NCH = S / CH;    // 8
constexpr int NPAIR = NCH * (NCH + 1) / 2;   // 36

constexpr int TSZ  = 128 * 32; // 128-row LDS tile (elems, 8 KB)
constexpr int TA64 = 64 * 32;  // 64-row LDS tile (elems, 4 KB)

// s_waitcnt immediates: vmcnt=N, expcnt=7 (ignore), lgkmcnt=15 (ignore)
#define WAIT_VM4 0x0F74
#define WAIT_VM3 0x0F73
#define WAIT_VM0 0x0F70

typedef __attribute__((ext_vector_type(8))) short short8;   // 8 bf16
typedef __attribute__((ext_vector_type(4))) float floatx4;  // 4 fp32

__device__ __forceinline__ float elu1(float x) { return x > 0.f ? x + 1.f : __expf(x); }
__device__ __forceinline__ float sigmoidf_(float x) { return 1.f / (1.f + __expf(-x)); }
__device__ __forceinline__ unsigned short f2bf(float x) {
    unsigned u = __float_as_uint(x);
    return (unsigned short)((u + 0x7fffu + ((u >> 16) & 1u)) >> 16);
}
__device__ __forceinline__ float bf2f(unsigned short h) {
    return __uint_as_float(((unsigned)h) << 16);
}
__device__ __forceinline__ float wave_reduce(float x) {
#pragma unroll
    for (int off = 32; off > 0; off >>= 1) x += __shfl_down(x, off);
    return x;
}

// async global->LDS, 16B per lane
__device__ __forceinline__ void gl_lds16(const unsigned short* g, unsigned short* l) {
    __builtin_amdgcn_global_load_lds(
        (const __attribute__((address_space(1))) void*)g,
        (__attribute__((address_space(3))) void*)l, 16, 0, 0);
}

// stage a 128x32 bf16 tile into LDS row-major [128][32]  (2 loads/thread)
__device__ __forceinline__ void stage128x32(const unsigned short* g, int stride,
                                            unsigned short* lds, int wave, int lane) {
    const int t   = (wave << 6) + lane;
    const int row = t >> 2;
    const int cb  = (t & 3) << 3;
    unsigned short* l0 = lds + (wave << 9);
    gl_lds16(g + (size_t)row * stride + cb, l0);
    gl_lds16(g + (size_t)(row + 64) * stride + cb, l0 + 2048);
}

// stage a 64x32 bf16 tile into LDS row-major [64][32]  (1 load/thread)
__device__ __forceinline__ void stage64x32(const unsigned short* g, int stride,
                                           unsigned short* lds, int wave, int lane) {
    const int t   = (wave << 6) + lane;
    const int row = t >> 2;
    const int cb  = (t & 3) << 3;
    gl_lds16(g + (size_t)row * stride + cb, lds + (wave << 9));
}

// 16 MFMAs, 128x128 tile, wave quadrant (wm,wn in {0,64})
__device__ __forceinline__ void mfma_step(const unsigned short* As, const unsigned short* Bs,
                                          int wm, int wn, int fr, int fo, floatx4 acc[4][4]) {
    short8 af[4], bf[4];
#pragma unroll
    for (int i = 0; i < 4; ++i) af[i] = *(const short8*)&As[(wm + i * 16 + fr) * 32 + fo];
#pragma unroll
    for (int j = 0; j < 4; ++j) bf[j] = *(const short8*)&Bs[(wn + j * 16 + fr) * 32 + fo];
#pragma unroll
    for (int i = 0; i < 4; ++i)
#pragma unroll
        for (int j = 0; j < 4; ++j)
            acc[i][j] = __builtin_amdgcn_mfma_f32_16x16x32_bf16(af[i], bf[j], acc[i][j], 0, 0, 0);
}

// 8 MFMAs, 64x128 tile (wm in {0,32}, wn in {0,64})
__device__ __forceinline__ void mfma_step64(const unsigned short* As, const unsigned short* Bs,
                                            int wm, int wn, int fr, int fo, floatx4 acc[2][4]) {
    short8 af[2], bf[4];
#pragma unroll
    for (int i = 0; i < 2; ++i) af[i] = *(const short8*)&As[(wm + i * 16 + fr) * 32 + fo];
#pragma unroll
    for (int j = 0; j < 4; ++j) bf[j] = *(const short8*)&Bs[(wn + j * 16 + fr) * 32 + fo];
#pragma unroll
    for (int i = 0; i < 2; ++i)
#pragma unroll
        for (int j = 0; j < 4; ++j)
            acc[i][j] = __builtin_amdgcn_mfma_f32_16x16x32_bf16(af[i], bf[j], acc[i][j], 0, 0, 0);
}

// 3-buffer ring K-loop, 128x128 tile. Raw s_barrier + manual vmcnt: prefetch depth
// = 2 iterations (stage(i) consumed at iter i, issued at iter i-2).
// Per iter: [waitcnt vmcnt(4) -> own stage(i) drained] [s_barrier -> ALL stage(i)
// drained + all iter-(i-1) LDS reads done] [issue stage(i+2) -> WAR-safe] [mfma(i)].
__device__ __forceinline__ void gemm_ring128(const unsigned short* Ag, int strideA,
                                             const unsigned short* Bg, int strideB, int Kk,
                                             unsigned short* As, unsigned short* Bs,
                                             int wave, int lane, int wm, int wn, int fr, int fo,
                                             floatx4 acc[4][4]) {
    const int T = Kk >> 5;
    stage128x32(Ag, strideA, As, wave, lane);
    stage128x32(Bg, strideB, Bs, wave, lane);
    if (T > 1) {
        stage128x32(Ag + 32, strideA, As + TSZ, wave, lane);
        stage128x32(Bg + 32, strideB, Bs + TSZ, wave, lane);
    }
    int cur = 0;
    for (int i = 0; i < T; ++i) {
        if (i + 1 < T) __builtin_amdgcn_s_waitcnt(WAIT_VM4);
        else           __builtin_amdgcn_s_waitcnt(WAIT_VM0);
        asm volatile("" ::: "memory");
        __builtin_amdgcn_s_barrier();
        asm volatile("" ::: "memory");
        if (i + 2 < T) {
            int nb = cur + 2; if (nb >= 3) nb -= 3;
            stage128x32(Ag + (size_t)(i + 2) * 32, strideA, As + nb * TSZ, wave, lane);
            stage128x32(Bg + (size_t)(i + 2) * 32, strideB, Bs + nb * TSZ, wave, lane);
        }
        mfma_step(As + cur * TSZ, Bs + cur * TSZ, wm, wn, fr, fo, acc);
        ++cur; if (cur == 3) cur = 0;
    }
}

// 3-buffer ring, 64x128 tile (3 loads/thread/iter -> vmcnt(3))
__device__ __forceinline__ void gemm_ring64(const unsigned short* Ag, int strideA,
                                            const unsigned short* Bg, int strideB, int Kk,
                                            unsigned short* As, unsigned short* Bs,
                                            int wave, int lane, int wm, int wn, int fr, int fo,
                                            floatx4 acc[2][4]) {
    const int T = Kk >> 5;
    stage64x32(Ag, strideA, As, wave, lane);
    stage128x32(Bg, strideB, Bs, wave, lane);
    if (T > 1) {
        stage64x32(Ag + 32, strideA, As + TA64, wave, lane);
        stage128x32(Bg + 32, strideB, Bs + TSZ, wave, lane);
    }
    int cur = 0;
    for (int i = 0; i < T; ++i) {
        if (i + 1 < T) __builtin_amdgcn_s_waitcnt(WAIT_VM3);
        else           __builtin_amdgcn_s_waitcnt(WAIT_VM0);
        asm volatile("" ::: "memory");
        __builtin_amdgcn_s_barrier();
        asm volatile("" ::: "memory");
        if (i + 2 < T) {
            int nb = cur + 2; if (nb >= 3) nb -= 3;
            stage64x32(Ag + (size_t)(i + 2) * 32, strideA, As + nb * TA64, wave, lane);
            stage128x32(Bg + (size_t)(i + 2) * 32, strideB, Bs + nb * TSZ, wave, lane);
        }
        mfma_step64(As + cur * TA64, Bs + cur * TSZ, wm, wn, fr, fo, acc);
        ++cur; if (cur == 3) cur = 0;
    }
}

// ---------------- prep: cvt h + cvt 4 weights + transpose memory ----------------
__global__ __launch_bounds__(256) void prep(const float* __restrict__ h,
                                            const float* __restrict__ w_q, const float* __restrict__ w_k,
                                            const float* __restrict__ w_v, const float* __restrict__ w_o,
                                            const float* __restrict__ memory,
                                            unsigned short* __restrict__ h_b,
                                            unsigned short* __restrict__ wq_b, unsigned short* __restrict__ wk_b,
                                            unsigned short* __restrict__ wv_b, unsigned short* __restrict__ wo_b,
                                            unsigned short* __restrict__ memT)
{
    __shared__ unsigned short T[64][72];
    const int id = blockIdx.x, tid = threadIdx.x;
    if (id < 4096) {
        const size_t i = ((size_t)id * 256 + tid) * 4;
        float4 v = *(const float4*)(h + i);
        ushort4 o; o.x = f2bf(v.x); o.y = f2bf(v.y); o.z = f2bf(v.z); o.w = f2bf(v.w);
        *(ushort4*)(h_b + i) = o;
    } else if (id < 8192) {
        const int t = id - 4096, which = t >> 10;
        const float* in = (which == 0) ? w_q : (which == 1) ? w_k : (which == 2) ? w_v : w_o;
        unsigned short* out = (which == 0) ? wq_b : (which == 1) ? wk_b : (which == 2) ? wv_b : wo_b;
        const size_t i = ((size_t)(t & 1023) * 256 + tid) * 4;
        float4 v = *(const float4*)(in + i);
        ushort4 o; o.x = f2bf(v.x); o.y = f2bf(v.y); o.z = f2bf(v.z); o.w = f2bf(v.w);
        *(ushort4*)(out + i) = o;
    } else {
        const int t = id - 8192;
        const int d0 = (t >> 4) * 64, e0 = (t & 15) * 64;
        const int r = tid >> 4, c4 = (tid & 15) * 4;
        for (int rr = r; rr < 64; rr += 16) {
            float4 v = *(const float4*)(memory + (size_t)(d0 + rr) * D + e0 + c4);
            T[rr][c4 + 0] = f2bf(v.x); T[rr][c4 + 1] = f2bf(v.y);
            T[rr][c4 + 2] = f2bf(v.z); T[rr][c4 + 3] = f2bf(v.w);
        }
        __syncthreads();
        for (int rr = r; rr < 64; rr += 16) {
            ushort4 o;
            o.x = T[c4 + 0][rr]; o.y = T[c4 + 1][rr];
            o.z = T[c4 + 2][rr]; o.w = T[c4 + 3][rr];
            *(ushort4*)(memT + (size_t)(e0 + rr) * D + d0 + c4) = o;
        }
    }
}

// ---------------- fused q/k/v projections: 768 blocks ----------------
__global__ __launch_bounds__(256) void proj_fused(const unsigned short* __restrict__ h_b,
                                                  const unsigned short* __restrict__ wq,
                                                  const unsigned short* __restrict__ wk,
                                                  const unsigned short* __restrict__ wv,
                                                  unsigned short* __restrict__ sq,
                                                  unsigned short* __restrict__ sk,
                                                  unsigned short* __restrict__ v)
{
    __shared__ unsigned short As[3 * TSZ], Bs[3 * TSZ];
    const int id = blockIdx.x;
    const int sub = id >> 8, t = id & 255;
    const int m0 = (t >> 3) * 128, n0 = (t & 7) * 128;
    const unsigned short* B = (sub == 0) ? wq : (sub == 1) ? wk : wv;
    unsigned short* C = (sub == 0) ? sq : (sub == 1) ? sk : v;

    const int tid = threadIdx.x, wave = tid >> 6, lane = tid & 63;
    const int wm = (wave >> 1) * 64, wn = (wave & 1) * 64;
    const int fr = lane & 15, fo = (lane >> 4) * 8;
    const int q4 = (lane >> 4) * 4;

    floatx4 acc[4][4] = {};
    gemm_ring128(h_b + (size_t)m0 * D, D, B + (size_t)n0 * D, D, D,
                 As, Bs, wave, lane, wm, wn, fr, fo, acc);

#pragma unroll
    for (int i = 0; i < 4; ++i)
#pragma unroll
        for (int j = 0; j < 4; ++j) {
            const int col = n0 + wn + j * 16 + fr;
#pragma unroll
            for (int r = 0; r < 4; ++r) {
                const int row = m0 + wm + i * 16 + q4 + r;
                float val = acc[i][j][r];
                if (sub < 2) val = elu1(val);
                C[(size_t)row * D + col] = f2bf(val);
            }
        }
}

// ---------------- stage2: memgemm(256, bf16 out) + scores(288, Sbuf2 layout) + v-transpose(1024)
// Sbuf2 layout: [b][c][row 0..255][col 0..S) — row-contiguous over ALL j slabs.
__global__ __launch_bounds__(256) void stage2(const unsigned short* __restrict__ sq,
                                              const unsigned short* __restrict__ sk,
                                              const unsigned short* __restrict__ memT,
                                              const unsigned short* __restrict__ v_b,
                                              unsigned short* __restrict__ combm,
                                              unsigned short* __restrict__ Sbuf2,
                                              unsigned short* __restrict__ vT)
{
    __shared__ unsigned short As[3 * TSZ], Bs[3 * TSZ];
    const int id = blockIdx.x, tid = threadIdx.x;
    const int wave = tid >> 6, lane = tid & 63;
    const int wm = (wave >> 1) * 64, wn = (wave & 1) * 64;
    const int fr = lane & 15, fo = (lane >> 4) * 8;
    const int q4 = (lane >> 4) * 4;

    if (id < 256) {
        // combm = f2bf(sq @ memT^T)
        const int m0 = (id >> 3) * 128, n0 = (id & 7) * 128;
        floatx4 acc[4][4] = {};
        gemm_ring128(sq + (size_t)m0 * D, D, memT + (size_t)n0 * D, D, D,
                     As, Bs, wave, lane, wm, wn, fr, fo, acc);
#pragma unroll
        for (int i = 0; i < 4; ++i)
#pragma unroll
            for (int j = 0; j < 4; ++j) {
                const int col = n0 + wn + j * 16 + fr;
#pragma unroll
                for (int r = 0; r < 4; ++r)
                    combm[(size_t)(m0 + wm + i * 16 + q4 + r) * D + col] = f2bf(acc[i][j][r]);
            }
    } else if (id < 544) {
        // scores pair (c,j): rows of chunk c, col slab j*CH
        const int t = id - 256;
        const int b = t / 144, rem = t % 144;
        const int p = rem >> 2, tt = rem & 3;
        const int it = tt >> 1, jt = tt & 1;
        int c = 0;
        while ((c + 1) * (c + 2) / 2 <= p) ++c;
        const int j = p - c * (c + 1) / 2;
        unsigned short* Srow0 = Sbuf2 + (size_t)(b * NCH + c) * CH * S;   // + row*S + col

        if (j == c && jt > it) {  // fully above diagonal: zero-fill
            const int row = it * 128 + (tid >> 1);
            unsigned short* zp = Srow0 + (size_t)row * S + j * CH + jt * 128 + (tid & 1) * 64;
            uint4 z4 = make_uint4(0, 0, 0, 0);
#pragma unroll
            for (int i = 0; i < 8; ++i) *(uint4*)(zp + i * 8) = z4;
            return;
        }
        floatx4 acc[4][4] = {};
        gemm_ring128(sq + ((size_t)b * S + (size_t)c * CH + it * 128) * D, D,
                     sk + ((size_t)b * S + (size_t)j * CH + jt * 128) * D, D, D,
                     As, Bs, wave, lane, wm, wn, fr, fo, acc);
        const bool diag = (j == c && it == jt);
#pragma unroll
        for (int i = 0; i < 4; ++i)
#pragma unroll
            for (int jj = 0; jj < 4; ++jj) {
                const int col = jt * 128 + wn + jj * 16 + fr;   // within slab
#pragma unroll
                for (int r = 0; r < 4; ++r) {
                    const int row = it * 128 + wm + i * 16 + q4 + r;
                    float val = acc[i][jj][r];
                    if (diag && col > row) val = 0.f;
                    Srow0[(size_t)row * S + j * CH + col] = f2bf(val);
                }
            }
    } else {
        // transpose v_b [b][s][d] -> vT [b][d][s], 64x64 tiles
        unsigned short (*T)[72] = (unsigned short(*)[72])As;
        const int t = id - 544;
        const int b = t >> 9, rem = t & 511;
        const int s0 = (rem >> 4) * 64, d0 = (rem & 15) * 64;
        const int r = tid >> 4, c4 = (tid & 15) * 4;
        const unsigned short* ip = v_b + (size_t)b * S * D;
        for (int rr = r; rr < 64; rr += 16) {
            ushort4 vv = *(const ushort4*)(ip + (size_t)(s0 + rr) * D + d0 + c4);
            T[rr][c4 + 0] = vv.x; T[rr][c4 + 1] = vv.y; T[rr][c4 + 2] = vv.z; T[rr][c4 + 3] = vv.w;
        }
        __syncthreads();
        unsigned short* op = vT + (size_t)b * D * S;
        for (int rr = r; rr < 64; rr += 16) {
            ushort4 o;
            o.x = T[c4 + 0][rr]; o.y = T[c4 + 1][rr];
            o.z = T[c4 + 2][rr]; o.w = T[c4 + 3][rr];
            *(ushort4*)(op + (size_t)(d0 + rr) * S + s0 + c4) = o;
        }
    }
}

// ---------------- epi1: rowscale (1024) + den rowsum (1024) ----------------
__global__ __launch_bounds__(256) void epi1(const unsigned short* __restrict__ sq,
                                            const float* __restrict__ mnorm,
                                            const float* __restrict__ gate,
                                            const unsigned short* __restrict__ Sbuf2,
                                            float* __restrict__ rowscale,
                                            float* __restrict__ den)
{
    const int id = blockIdx.x;
    const int wave = threadIdx.x >> 6, lane = threadIdx.x & 63;
    if (id < 1024) {
        // rowscale[row] = g*active / clip(sq_row . mnorm)
        const int row = id * 4 + wave;
        const unsigned short* sr = sq + (size_t)row * D;
        float dot = 0.f, msum = 0.f;
        for (int d = lane; d < D; d += 64) {
            float mn = mnorm[d];
            dot += bf2f(sr[d]) * mn;
            msum += mn;
        }
        dot = wave_reduce(dot);
        msum = wave_reduce(msum);
        if (lane == 0) {
            const float g = sigmoidf_(gate[0]);
            const float active = (msum >= EPSF) ? 1.f : 0.f;
            rowscale[row] = g * active / fmaxf(dot, EPSF);
        }
    } else {
        // den[r] = contiguous rowsum of Sbuf2 row (length (c+1)*CH)
        const int r = (id - 1024) * 4 + wave;
        const int b = r / S, sr_ = r % S, c = sr_ >> 8, i = sr_ & 255;
        const unsigned short* rp = Sbuf2 + ((size_t)(b * NCH + c) * CH + i) * S;
        const int len = (c + 1) * CH;
        float s = 0.f;
        for (int d0 = lane * 4; d0 < len; d0 += 256) {
            ushort4 a4 = *(const ushort4*)(rp + d0);
            s += bf2f(a4.x) + bf2f(a4.y) + bf2f(a4.z) + bf2f(a4.w);
        }
        s = wave_reduce(s);
        if (lane == 0) den[r] = s;
    }
}

// ---------------- pv: combm = f2bf(combm*rowscale + (1-g)*(S@v)/den) in place, 512 blocks ------
__global__ __launch_bounds__(256) void pv64(const unsigned short* __restrict__ Sbuf2,
                                            const unsigned short* __restrict__ vT,
                                            const float* __restrict__ den,
                                            const float* __restrict__ rowscale,
                                            const float* __restrict__ gate,
                                            unsigned short* __restrict__ combm)
{
    __shared__ unsigned short As2[3 * TA64], Bs2[3 * TSZ];
    const int id = blockIdx.x, tid = threadIdx.x;
    const int wave = tid >> 6, lane = tid & 63;
    const int wm = (wave >> 1) * 32, wn = (wave & 1) * 64;
    const int fr = lane & 15, fo = (lane >> 4) * 8;
    const int q4 = (lane >> 4) * 4;

    const int bc = id >> 5, rem = id & 31;
    const int b = bc >> 3;
    const int c = (NCH - 1) - (bc & 7);           // long-K blocks first
    const int i0 = (rem >> 3) * 64, e0 = (rem & 7) * 128;

    floatx4 acc[2][4] = {};
    gemm_ring64(Sbuf2 + ((size_t)(b * NCH + c) * CH + i0) * S, S,
                vT + (size_t)b * D * S + (size_t)e0 * S, S, (c + 1) * CH,
                As2, Bs2, wave, lane, wm, wn, fr, fo, acc);

    const float g = sigmoidf_(gate[0]);
    const float wloc = 1.f - g;
#pragma unroll
    for (int i = 0; i < 2; ++i)
#pragma unroll
        for (int j = 0; j < 4; ++j) {
            const int col = e0 + wn + j * 16 + fr;
#pragma unroll
            for (int r = 0; r < 4; ++r) {
                const int li = i0 + wm + i * 16 + q4 + r;
                const int rg = b * S + c * CH + li;
                const float inv = wloc / fmaxf(den[rg], EPSF);
                const size_t idx = (size_t)rg * D + col;
                combm[idx] = f2bf(bf2f(combm[idx]) * rowscale[rg] + acc[i][j][r] * inv);
            }
        }
}

// ---------------- out-proj: out = combm @ wo^T (fp32), 512 blocks ----------------
__global__ __launch_bounds__(256) void outproj64(const unsigned short* __restrict__ A,
                                                 const unsigned short* __restrict__ wo,
                                                 float* __restrict__ out)
{
    __shared__ unsigned short As2[3 * TA64], Bs2[3 * TSZ];
    const int id = blockIdx.x, tid = threadIdx.x;
    const int wave = tid >> 6, lane = tid & 63;
    const int wm = (wave >> 1) * 32, wn = (wave & 1) * 64;
    const int fr = lane & 15, fo = (lane >> 4) * 8;
    const int q4 = (lane >> 4) * 4;
    const int m0 = (id >> 3) * 64, n0 = (id & 7) * 128;

    floatx4 acc[2][4] = {};
    gemm_ring64(A + (size_t)m0 * D, D, wo + (size_t)n0 * D, D, D,
                As2, Bs2, wave, lane, wm, wn, fr, fo, acc);

#pragma unroll
    for (int i = 0; i < 2; ++i)
#pragma unroll
        for (int j = 0; j < 4; ++j) {
            const int col = n0 + wn + j * 16 + fr;
#pragma unroll
            for (int r = 0; r < 4; ++r)
                out[(size_t)(m0 + wm + i * 16 + q4 + r) * D + col] = acc[i][j][r];
        }
}

extern "C" void kernel_launch(void* const* d_in, const int* in_sizes, int n_in,
                              void* d_out, int out_size, void* d_ws, size_t ws_size,
                              hipStream_t stream)
{
    const float* h      = (const float*)d_in[0];
    const float* w_q    = (const float*)d_in[1];
    const float* w_k    = (const float*)d_in[2];
    const float* w_v    = (const float*)d_in[3];
    const float* w_o    = (const float*)d_in[4];
    const float* gate   = (const float*)d_in[5];
    const float* memory = (const float*)d_in[6];
    const float* mnorm  = (const float*)d_in[7];
    float* out = (float*)d_out;

    // ---- workspace (~75 MB), no aliasing ----
    unsigned short* h_b   = (unsigned short*)d_ws;               // M*D (8 MB)
    unsigned short* wq_b  = h_b + (size_t)M * D;                 // D*D
    unsigned short* wk_b  = wq_b + (size_t)D * D;                // D*D
    unsigned short* wv_b  = wk_b + (size_t)D * D;                // D*D
    unsigned short* wo_b  = wv_b + (size_t)D * D;                // D*D
    unsigned short* memT  = wo_b + (size_t)D * D;                // D*D (2 MB)
    unsigned short* sq_b  = memT + (size_t)D * D;                // M*D (8 MB)
    unsigned short* sk_b  = sq_b + (size_t)M * D;                // M*D (8 MB)
    unsigned short* v_b   = sk_b + (size_t)M * D;                // M*D (8 MB)
    unsigned short* vT    = v_b + (size_t)M * D;                 // M*D (8 MB)
    unsigned short* Sbuf2 = vT + (size_t)M * D;                  // Bv*NCH*CH*S (16.8 MB)
    unsigned short* combm = Sbuf2 + (size_t)Bv * NCH * CH * S;   // M*D (8 MB)
    float* rowscale = (float*)(combm + (size_t)M * D);           // M fp32
    float* den      = rowscale + M;                              // M fp32

    dim3 blk(256);

    prep<<<8448, blk, 0, stream>>>(h, w_q, w_k, w_v, w_o, memory,
                                   h_b, wq_b, wk_b, wv_b, wo_b, memT);
    proj_fused<<<768, blk, 0, stream>>>(h_b, wq_b, wk_b, wv_b, sq_b, sk_b, v_b);
    stage2<<<1568, blk, 0, stream>>>(sq_b, sk_b, memT, v_b, combm, Sbuf2, vT);
    epi1<<<2048, blk, 0, stream>>>(sq_b, mnorm, gate, Sbuf2, rowscale, den);
    pv64<<<512, blk, 0, stream>>>(Sbuf2, vT, den, rowscale, gate, combm);
    outproj64<<<512, blk, 0, stream>>>(combm, wo_b, out);
}

// Round 9
// 237.352 us; speedup vs baseline: 1.0891x; 1.0891x over previous
//
#include <hip/hip_runtime.h>
#include <cstddef>

#define EPSF 1e-6f

constexpr int D   = 1024;
constexpr int Bv  = 2;
constexpr int S   = 2048;
constexpr int M   = Bv * S;    // 4096
constexpr int CH  = 256;       // chunk
constexpr int NCH = S / CH;    // 8

constexpr int TSZ  = 128 * 32; // 128-row LDS tile (elems, 8 KB)
constexpr int TA64 = 64 * 32;  // 64-row LDS tile (elems, 4 KB)

typedef __attribute__((ext_vector_type(8))) short short8;   // 8 bf16
typedef __attribute__((ext_vector_type(4))) float floatx4;  // 4 fp32

__device__ __forceinline__ float elu1(float x) { return x > 0.f ? x + 1.f : __expf(x); }
__device__ __forceinline__ float sigmoidf_(float x) { return 1.f / (1.f + __expf(-x)); }
__device__ __forceinline__ unsigned short f2bf(float x) {
    unsigned u = __float_as_uint(x);
    return (unsigned short)((u + 0x7fffu + ((u >> 16) & 1u)) >> 16);
}
__device__ __forceinline__ float bf2f(unsigned short h) {
    return __uint_as_float(((unsigned)h) << 16);
}
__device__ __forceinline__ float wave_reduce(float x) {
#pragma unroll
    for (int off = 32; off > 0; off >>= 1) x += __shfl_down(x, off);
    return x;
}

// async global->LDS, 16B per lane
__device__ __forceinline__ void gl_lds16(const unsigned short* g, unsigned short* l) {
    __builtin_amdgcn_global_load_lds(
        (const __attribute__((address_space(1))) void*)g,
        (__attribute__((address_space(3))) void*)l, 16, 0, 0);
}

// stage a 128x32 bf16 tile into LDS row-major [128][32]  (2 loads/thread)
__device__ __forceinline__ void stage128x32(const unsigned short* g, int stride,
                                            unsigned short* lds, int wave, int lane) {
    const int t   = (wave << 6) + lane;
    const int row = t >> 2;
    const int cb  = (t & 3) << 3;
    unsigned short* l0 = lds + (wave << 9);
    gl_lds16(g + (size_t)row * stride + cb, l0);
    gl_lds16(g + (size_t)(row + 64) * stride + cb, l0 + 2048);
}

// stage a 64x32 bf16 tile into LDS row-major [64][32]  (1 load/thread)
__device__ __forceinline__ void stage64x32(const unsigned short* g, int stride,
                                           unsigned short* lds, int wave, int lane) {
    const int t   = (wave << 6) + lane;
    const int row = t >> 2;
    const int cb  = (t & 3) << 3;
    gl_lds16(g + (size_t)row * stride + cb, lds + (wave << 9));
}

// 16 MFMAs, 128x128 tile, wave quadrant (wm,wn in {0,64})
__device__ __forceinline__ void mfma_step(const unsigned short* As, const unsigned short* Bs,
                                          int wm, int wn, int fr, int fo, floatx4 acc[4][4]) {
    short8 af[4], bf[4];
#pragma unroll
    for (int i = 0; i < 4; ++i) af[i] = *(const short8*)&As[(wm + i * 16 + fr) * 32 + fo];
#pragma unroll
    for (int j = 0; j < 4; ++j) bf[j] = *(const short8*)&Bs[(wn + j * 16 + fr) * 32 + fo];
#pragma unroll
    for (int i = 0; i < 4; ++i)
#pragma unroll
        for (int j = 0; j < 4; ++j)
            acc[i][j] = __builtin_amdgcn_mfma_f32_16x16x32_bf16(af[i], bf[j], acc[i][j], 0, 0, 0);
}

// 8 MFMAs + 2 ones-MFMAs (rowsum), 64x128 tile (wm in {0,32}, wn in {0,64})
__device__ __forceinline__ void mfma_step64d(const unsigned short* As, const unsigned short* Bs,
                                             int wm, int wn, int fr, int fo,
                                             floatx4 acc[2][4], floatx4 accd[2], short8 bones) {
    short8 af[2], bf[4];
#pragma unroll
    for (int i = 0; i < 2; ++i) af[i] = *(const short8*)&As[(wm + i * 16 + fr) * 32 + fo];
#pragma unroll
    for (int j = 0; j < 4; ++j) bf[j] = *(const short8*)&Bs[(wn + j * 16 + fr) * 32 + fo];
#pragma unroll
    for (int i = 0; i < 2; ++i) {
#pragma unroll
        for (int j = 0; j < 4; ++j)
            acc[i][j] = __builtin_amdgcn_mfma_f32_16x16x32_bf16(af[i], bf[j], acc[i][j], 0, 0, 0);
        accd[i] = __builtin_amdgcn_mfma_f32_16x16x32_bf16(af[i], bones, accd[i], 0, 0, 0);
    }
}

// 8 MFMAs, 64x128 tile (no rowsum)
__device__ __forceinline__ void mfma_step64(const unsigned short* As, const unsigned short* Bs,
                                            int wm, int wn, int fr, int fo, floatx4 acc[2][4]) {
    short8 af[2], bf[4];
#pragma unroll
    for (int i = 0; i < 2; ++i) af[i] = *(const short8*)&As[(wm + i * 16 + fr) * 32 + fo];
#pragma unroll
    for (int j = 0; j < 4; ++j) bf[j] = *(const short8*)&Bs[(wn + j * 16 + fr) * 32 + fo];
#pragma unroll
    for (int i = 0; i < 2; ++i)
#pragma unroll
        for (int j = 0; j < 4; ++j)
            acc[i][j] = __builtin_amdgcn_mfma_f32_16x16x32_bf16(af[i], bf[j], acc[i][j], 0, 0, 0);
}

// Double-buffered K-loop (round-7 proven), 128x128 tile.
__device__ __forceinline__ void gemm_loop_db(const unsigned short* Ag, int strideA,
                                             const unsigned short* Bg, int strideB, int Kk,
                                             unsigned short* As, unsigned short* Bs,
                                             int wave, int lane, int wm, int wn, int fr, int fo,
                                             floatx4 acc[4][4]) {
    __syncthreads();
    stage128x32(Ag, strideA, As, wave, lane);
    stage128x32(Bg, strideB, Bs, wave, lane);
    int buf = 0;
    for (int k0 = 32; k0 < Kk; k0 += 32) {
        __syncthreads();
        const int nb = buf ^ 1;
        stage128x32(Ag + k0, strideA, As + nb * TSZ, wave, lane);
        stage128x32(Bg + k0, strideB, Bs + nb * TSZ, wave, lane);
        mfma_step(As + buf * TSZ, Bs + buf * TSZ, wm, wn, fr, fo, acc);
        buf = nb;
    }
    __syncthreads();
    mfma_step(As + buf * TSZ, Bs + buf * TSZ, wm, wn, fr, fo, acc);
}

// Double-buffered K-loop, 64x128 tile, with in-register rowsum (den)
__device__ __forceinline__ void gemm_loop_db64d(const unsigned short* Ag, int strideA,
                                                const unsigned short* Bg, int strideB, int Kk,
                                                unsigned short* As, unsigned short* Bs,
                                                int wave, int lane, int wm, int wn, int fr, int fo,
                                                floatx4 acc[2][4], floatx4 accd[2], short8 bones) {
    __syncthreads();
    stage64x32(Ag, strideA, As, wave, lane);
    stage128x32(Bg, strideB, Bs, wave, lane);
    int buf = 0;
    for (int k0 = 32; k0 < Kk; k0 += 32) {
        __syncthreads();
        const int nb = buf ^ 1;
        stage64x32(Ag + k0, strideA, As + nb * TA64, wave, lane);
        stage128x32(Bg + k0, strideB, Bs + nb * TSZ, wave, lane);
        mfma_step64d(As + buf * TA64, Bs + buf * TSZ, wm, wn, fr, fo, acc, accd, bones);
        buf = nb;
    }
    __syncthreads();
    mfma_step64d(As + buf * TA64, Bs + buf * TSZ, wm, wn, fr, fo, acc, accd, bones);
}

// Double-buffered K-loop, 64x128 tile (plain)
__device__ __forceinline__ void gemm_loop_db64(const unsigned short* Ag, int strideA,
                                               const unsigned short* Bg, int strideB, int Kk,
                                               unsigned short* As, unsigned short* Bs,
                                               int wave, int lane, int wm, int wn, int fr, int fo,
                                               floatx4 acc[2][4]) {
    __syncthreads();
    stage64x32(Ag, strideA, As, wave, lane);
    stage128x32(Bg, strideB, Bs, wave, lane);
    int buf = 0;
    for (int k0 = 32; k0 < Kk; k0 += 32) {
        __syncthreads();
        const int nb = buf ^ 1;
        stage64x32(Ag + k0, strideA, As + nb * TA64, wave, lane);
        stage128x32(Bg + k0, strideB, Bs + nb * TSZ, wave, lane);
        mfma_step64(As + buf * TA64, Bs + buf * TSZ, wm, wn, fr, fo, acc);
        buf = nb;
    }
    __syncthreads();
    mfma_step64(As + buf * TA64, Bs + buf * TSZ, wm, wn, fr, fo, acc);
}

// ---------------- prep: cvt h + cvt 4 weights + transpose memory ----------------
__global__ __launch_bounds__(256) void prep(const float* __restrict__ h,
                                            const float* __restrict__ w_q, const float* __restrict__ w_k,
                                            const float* __restrict__ w_v, const float* __restrict__ w_o,
                                            const float* __restrict__ memory,
                                            unsigned short* __restrict__ h_b,
                                            unsigned short* __restrict__ wq_b, unsigned short* __restrict__ wk_b,
                                            unsigned short* __restrict__ wv_b, unsigned short* __restrict__ wo_b,
                                            unsigned short* __restrict__ memT)
{
    __shared__ unsigned short T[64][72];
    const int id = blockIdx.x, tid = threadIdx.x;
    if (id < 4096) {
        const size_t i = ((size_t)id * 256 + tid) * 4;
        float4 v = *(const float4*)(h + i);
        ushort4 o; o.x = f2bf(v.x); o.y = f2bf(v.y); o.z = f2bf(v.z); o.w = f2bf(v.w);
        *(ushort4*)(h_b + i) = o;
    } else if (id < 8192) {
        const int t = id - 4096, which = t >> 10;
        const float* in = (which == 0) ? w_q : (which == 1) ? w_k : (which == 2) ? w_v : w_o;
        unsigned short* out = (which == 0) ? wq_b : (which == 1) ? wk_b : (which == 2) ? wv_b : wo_b;
        const size_t i = ((size_t)(t & 1023) * 256 + tid) * 4;
        float4 v = *(const float4*)(in + i);
        ushort4 o; o.x = f2bf(v.x); o.y = f2bf(v.y); o.z = f2bf(v.z); o.w = f2bf(v.w);
        *(ushort4*)(out + i) = o;
    } else {
        const int t = id - 8192;
        const int d0 = (t >> 4) * 64, e0 = (t & 15) * 64;
        const int r = tid >> 4, c4 = (tid & 15) * 4;
        for (int rr = r; rr < 64; rr += 16) {
            float4 v = *(const float4*)(memory + (size_t)(d0 + rr) * D + e0 + c4);
            T[rr][c4 + 0] = f2bf(v.x); T[rr][c4 + 1] = f2bf(v.y);
            T[rr][c4 + 2] = f2bf(v.z); T[rr][c4 + 3] = f2bf(v.w);
        }
        __syncthreads();
        for (int rr = r; rr < 64; rr += 16) {
            ushort4 o;
            o.x = T[c4 + 0][rr]; o.y = T[c4 + 1][rr];
            o.z = T[c4 + 2][rr]; o.w = T[c4 + 3][rr];
            *(ushort4*)(memT + (size_t)(e0 + rr) * D + d0 + c4) = o;
        }
    }
}

// ---------------- fused q/k/v projections: 768 blocks ----------------
__global__ __launch_bounds__(256) void proj_fused(const unsigned short* __restrict__ h_b,
                                                  const unsigned short* __restrict__ wq,
                                                  const unsigned short* __restrict__ wk,
                                                  const unsigned short* __restrict__ wv,
                                                  unsigned short* __restrict__ sq,
                                                  unsigned short* __restrict__ sk,
                                                  unsigned short* __restrict__ v)
{
    __shared__ unsigned short As[2 * TSZ], Bs[2 * TSZ];
    const int id = blockIdx.x;
    const int sub = id >> 8, t = id & 255;
    const int m0 = (t >> 3) * 128, n0 = (t & 7) * 128;
    const unsigned short* B = (sub == 0) ? wq : (sub == 1) ? wk : wv;
    unsigned short* C = (sub == 0) ? sq : (sub == 1) ? sk : v;

    const int tid = threadIdx.x, wave = tid >> 6, lane = tid & 63;
    const int wm = (wave >> 1) * 64, wn = (wave & 1) * 64;
    const int fr = lane & 15, fo = (lane >> 4) * 8;
    const int q4 = (lane >> 4) * 4;

    floatx4 acc[4][4] = {};
    gemm_loop_db(h_b + (size_t)m0 * D, D, B + (size_t)n0 * D, D, D,
                 As, Bs, wave, lane, wm, wn, fr, fo, acc);

#pragma unroll
    for (int i = 0; i < 4; ++i)
#pragma unroll
        for (int j = 0; j < 4; ++j) {
            const int col = n0 + wn + j * 16 + fr;
#pragma unroll
            for (int r = 0; r < 4; ++r) {
                const int row = m0 + wm + i * 16 + q4 + r;
                float val = acc[i][j][r];
                if (sub < 2) val = elu1(val);
                C[(size_t)row * D + col] = f2bf(val);
            }
        }
}

// ---------------- stage2: memgemm(256) + scores(288) + v-transpose(1024) + rowscale(1024) ------
// Sbuf2 layout: [b][c][row 0..255][col 0..S) row-contiguous over all j slabs.
__global__ __launch_bounds__(256) void stage2(const unsigned short* __restrict__ sq,
                                              const unsigned short* __restrict__ sk,
                                              const unsigned short* __restrict__ memT,
                                              const unsigned short* __restrict__ v_b,
                                              const float* __restrict__ mnorm,
                                              const float* __restrict__ gate,
                                              unsigned short* __restrict__ combm,
                                              unsigned short* __restrict__ Sbuf2,
                                              unsigned short* __restrict__ vT,
                                              float* __restrict__ rowscale)
{
    __shared__ unsigned short As[2 * TSZ], Bs[2 * TSZ];
    const int id = blockIdx.x, tid = threadIdx.x;
    const int wave = tid >> 6, lane = tid & 63;
    const int wm = (wave >> 1) * 64, wn = (wave & 1) * 64;
    const int fr = lane & 15, fo = (lane >> 4) * 8;
    const int q4 = (lane >> 4) * 4;

    if (id < 256) {
        // combm = f2bf(sq @ memT^T)
        const int m0 = (id >> 3) * 128, n0 = (id & 7) * 128;
        floatx4 acc[4][4] = {};
        gemm_loop_db(sq + (size_t)m0 * D, D, memT + (size_t)n0 * D, D, D,
                     As, Bs, wave, lane, wm, wn, fr, fo, acc);
#pragma unroll
        for (int i = 0; i < 4; ++i)
#pragma unroll
            for (int j = 0; j < 4; ++j) {
                const int col = n0 + wn + j * 16 + fr;
#pragma unroll
                for (int r = 0; r < 4; ++r)
                    combm[(size_t)(m0 + wm + i * 16 + q4 + r) * D + col] = f2bf(acc[i][j][r]);
            }
    } else if (id < 544) {
        // scores pair (c,j): rows of chunk c, col slab j*CH
        const int t = id - 256;
        const int b = t / 144, rem = t % 144;
        const int p = rem >> 2, tt = rem & 3;
        const int it = tt >> 1, jt = tt & 1;
        int c = 0;
        while ((c + 1) * (c + 2) / 2 <= p) ++c;
        const int j = p - c * (c + 1) / 2;
        unsigned short* Srow0 = Sbuf2 + (size_t)(b * NCH + c) * CH * S;

        if (j == c && jt > it) {  // fully above diagonal: zero-fill
            const int row = it * 128 + (tid >> 1);
            unsigned short* zp = Srow0 + (size_t)row * S + j * CH + jt * 128 + (tid & 1) * 64;
            uint4 z4 = make_uint4(0, 0, 0, 0);
#pragma unroll
            for (int i = 0; i < 8; ++i) *(uint4*)(zp + i * 8) = z4;
            return;
        }
        floatx4 acc[4][4] = {};
        gemm_loop_db(sq + ((size_t)b * S + (size_t)c * CH + it * 128) * D, D,
                     sk + ((size_t)b * S + (size_t)j * CH + jt * 128) * D, D, D,
                     As, Bs, wave, lane, wm, wn, fr, fo, acc);
        const bool diag = (j == c && it == jt);
#pragma unroll
        for (int i = 0; i < 4; ++i)
#pragma unroll
            for (int jj = 0; jj < 4; ++jj) {
                const int col = jt * 128 + wn + jj * 16 + fr;   // within slab
#pragma unroll
                for (int r = 0; r < 4; ++r) {
                    const int row = it * 128 + wm + i * 16 + q4 + r;
                    float val = acc[i][jj][r];
                    if (diag && col > row) val = 0.f;
                    Srow0[(size_t)row * S + j * CH + col] = f2bf(val);
                }
            }
    } else if (id < 1568) {
        // transpose v_b [b][s][d] -> vT [b][d][s], 64x64 tiles
        unsigned short (*T)[72] = (unsigned short(*)[72])As;
        const int t = id - 544;
        const int b = t >> 9, rem = t & 511;
        const int s0 = (rem >> 4) * 64, d0 = (rem & 15) * 64;
        const int r = tid >> 4, c4 = (tid & 15) * 4;
        const unsigned short* ip = v_b + (size_t)b * S * D;
        for (int rr = r; rr < 64; rr += 16) {
            ushort4 vv = *(const ushort4*)(ip + (size_t)(s0 + rr) * D + d0 + c4);
            T[rr][c4 + 0] = vv.x; T[rr][c4 + 1] = vv.y; T[rr][c4 + 2] = vv.z; T[rr][c4 + 3] = vv.w;
        }
        __syncthreads();
        unsigned short* op = vT + (size_t)b * D * S;
        for (int rr = r; rr < 64; rr += 16) {
            ushort4 o;
            o.x = T[c4 + 0][rr]; o.y = T[c4 + 1][rr];
            o.z = T[c4 + 2][rr]; o.w = T[c4 + 3][rr];
            *(ushort4*)(op + (size_t)(d0 + rr) * S + s0 + c4) = o;
        }
    } else {
        // rowscale[row] = g*active / clip(sq_row . mnorm)
        const int row = (id - 1568) * 4 + wave;
        const unsigned short* sr = sq + (size_t)row * D;
        float dot = 0.f, msum = 0.f;
        for (int d = lane; d < D; d += 64) {
            float mn = mnorm[d];
            dot += bf2f(sr[d]) * mn;
            msum += mn;
        }
        dot = wave_reduce(dot);
        msum = wave_reduce(msum);
        if (lane == 0) {
            const float g = sigmoidf_(gate[0]);
            const float active = (msum >= EPSF) ? 1.f : 0.f;
            rowscale[row] = g * active / fmaxf(dot, EPSF);
        }
    }
}

// ---------------- pv: combm = f2bf(combm*rowscale + (1-g)*(S@v)/den), den in-register ----------
__global__ __launch_bounds__(256) void pv64(const unsigned short* __restrict__ Sbuf2,
                                            const unsigned short* __restrict__ vT,
                                            const float* __restrict__ rowscale,
                                            const float* __restrict__ gate,
                                            unsigned short* __restrict__ combm)
{
    __shared__ unsigned short As2[2 * TA64], Bs2[2 * TSZ];
    const int id = blockIdx.x, tid = threadIdx.x;
    const int wave = tid >> 6, lane = tid & 63;
    const int wm = (wave >> 1) * 32, wn = (wave & 1) * 64;
    const int fr = lane & 15, fo = (lane >> 4) * 8;
    const int q4 = (lane >> 4) * 4;

    const int bc = id >> 5, rem = id & 31;
    const int b = bc >> 3;
    const int c = (NCH - 1) - (bc & 7);           // long-K blocks first
    const int i0 = (rem >> 3) * 64, e0 = (rem & 7) * 128;

    const short one_bf = (short)0x3F80;
    short8 bones = {one_bf, one_bf, one_bf, one_bf, one_bf, one_bf, one_bf, one_bf};

    floatx4 acc[2][4] = {};
    floatx4 accd[2] = {};
    gemm_loop_db64d(Sbuf2 + ((size_t)(b * NCH + c) * CH + i0) * S, S,
                    vT + (size_t)b * D * S + (size_t)e0 * S, S, (c + 1) * CH,
                    As2, Bs2, wave, lane, wm, wn, fr, fo, acc, accd, bones);

    const float g = sigmoidf_(gate[0]);
    const float wloc = 1.f - g;
#pragma unroll
    for (int i = 0; i < 2; ++i)
#pragma unroll
        for (int j = 0; j < 4; ++j) {
            const int col = e0 + wn + j * 16 + fr;
#pragma unroll
            for (int r = 0; r < 4; ++r) {
                const int li = i0 + wm + i * 16 + q4 + r;
                const int rg = b * S + c * CH + li;
                const float inv = wloc / fmaxf(accd[i][r], EPSF);
                const size_t idx = (size_t)rg * D + col;
                combm[idx] = f2bf(bf2f(combm[idx]) * rowscale[rg] + acc[i][j][r] * inv);
            }
        }
}

// ---------------- out-proj: out = combm @ wo^T (fp32), 512 blocks ----------------
__global__ __launch_bounds__(256) void outproj64(const unsigned short* __restrict__ A,
                                                 const unsigned short* __restrict__ wo,
                                                 float* __restrict__ out)
{
    __shared__ unsigned short As2[2 * TA64], Bs2[2 * TSZ];
    const int id = blockIdx.x, tid = threadIdx.x;
    const int wave = tid >> 6, lane = tid & 63;
    const int wm = (wave >> 1) * 32, wn = (wave & 1) * 64;
    const int fr = lane & 15, fo = (lane >> 4) * 8;
    const int q4 = (lane >> 4) * 4;
    const int m0 = (id >> 3) * 64, n0 = (id & 7) * 128;

    floatx4 acc[2][4] = {};
    gemm_loop_db64(A + (size_t)m0 * D, D, wo + (size_t)n0 * D, D, D,
                   As2, Bs2, wave, lane, wm, wn, fr, fo, acc);

#pragma unroll
    for (int i = 0; i < 2; ++i)
#pragma unroll
        for (int j = 0; j < 4; ++j) {
            const int col = n0 + wn + j * 16 + fr;
#pragma unroll
            for (int r = 0; r < 4; ++r)
                out[(size_t)(m0 + wm + i * 16 + q4 + r) * D + col] = acc[i][j][r];
        }
}

extern "C" void kernel_launch(void* const* d_in, const int* in_sizes, int n_in,
                              void* d_out, int out_size, void* d_ws, size_t ws_size,
                              hipStream_t stream)
{
    const float* h      = (const float*)d_in[0];
    const float* w_q    = (const float*)d_in[1];
    const float* w_k    = (const float*)d_in[2];
    const float* w_v    = (const float*)d_in[3];
    const float* w_o    = (const float*)d_in[4];
    const float* gate   = (const float*)d_in[5];
    const float* memory = (const float*)d_in[6];
    const float* mnorm  = (const float*)d_in[7];
    float* out = (float*)d_out;

    // ---- workspace (~75 MB), no aliasing ----
    unsigned short* h_b   = (unsigned short*)d_ws;               // M*D (8 MB)
    unsigned short* wq_b  = h_b + (size_t)M * D;                 // D*D
    unsigned short* wk_b  = wq_b + (size_t)D * D;                // D*D
    unsigned short* wv_b  = wk_b + (size_t)D * D;                // D*D
    unsigned short* wo_b  = wv_b + (size_t)D * D;                // D*D
    unsigned short* memT  = wo_b + (size_t)D * D;                // D*D (2 MB)
    unsigned short* sq_b  = memT + (size_t)D * D;                // M*D (8 MB)
    unsigned short* sk_b  = sq_b + (size_t)M * D;                // M*D (8 MB)
    unsigned short* v_b   = sk_b + (size_t)M * D;                // M*D (8 MB)
    unsigned short* vT    = v_b + (size_t)M * D;                 // M*D (8 MB)
    unsigned short* Sbuf2 = vT + (size_t)M * D;                  // Bv*NCH*CH*S (16.8 MB)
    unsigned short* combm = Sbuf2 + (size_t)Bv * NCH * CH * S;   // M*D (8 MB)
    float* rowscale = (float*)(combm + (size_t)M * D);           // M fp32

    dim3 blk(256);

    prep<<<8448, blk, 0, stream>>>(h, w_q, w_k, w_v, w_o, memory,
                                   h_b, wq_b, wk_b, wv_b, wo_b, memT);
    proj_fused<<<768, blk, 0, stream>>>(h_b, wq_b, wk_b, wv_b, sq_b, sk_b, v_b);
    stage2<<<2592, blk, 0, stream>>>(sq_b, sk_b, memT, v_b, mnorm, gate,
                                     combm, Sbuf2, vT, rowscale);
    pv64<<<512, blk, 0, stream>>>(Sbuf2, vT, rowscale, gate, combm);
    outproj64<<<512, blk, 0, stream>>>(combm, wo_b, out);
}

// Round 10
// 231.627 us; speedup vs baseline: 1.1160x; 1.0247x over previous
//
#include <hip/hip_runtime.h>
#include <cstddef>

#define EPSF 1e-6f

constexpr int D   = 1024;
constexpr int Bv  = 2;
constexpr int S   = 2048;
constexpr int M   = Bv * S;    // 4096
constexpr int CH  = 256;       // chunk
constexpr int NCH = S / CH;    // 8

constexpr int TSZ  = 128 * 32; // 128-row LDS tile (elems, 8 KB)
constexpr int TA64 = 64 * 32;  // 64-row LDS tile (elems, 4 KB)

typedef __attribute__((ext_vector_type(8))) short short8;   // 8 bf16
typedef __attribute__((ext_vector_type(4))) float floatx4;  // 4 fp32

__device__ __forceinline__ float elu1(float x) { return x > 0.f ? x + 1.f : __expf(x); }
__device__ __forceinline__ float sigmoidf_(float x) { return 1.f / (1.f + __expf(-x)); }
__device__ __forceinline__ unsigned short f2bf(float x) {
    unsigned u = __float_as_uint(x);
    return (unsigned short)((u + 0x7fffu + ((u >> 16) & 1u)) >> 16);
}
__device__ __forceinline__ float bf2f(unsigned short h) {
    return __uint_as_float(((unsigned)h) << 16);
}
__device__ __forceinline__ float wave_reduce(float x) {
#pragma unroll
    for (int off = 32; off > 0; off >>= 1) x += __shfl_down(x, off);
    return x;
}

// async global->LDS, 16B per lane
__device__ __forceinline__ void gl_lds16(const unsigned short* g, unsigned short* l) {
    __builtin_amdgcn_global_load_lds(
        (const __attribute__((address_space(1))) void*)g,
        (__attribute__((address_space(3))) void*)l, 16, 0, 0);
}

// stage a 128x32 bf16 tile into LDS row-major [128][32]  (2 loads/thread)
__device__ __forceinline__ void stage128x32(const unsigned short* g, int stride,
                                            unsigned short* lds, int wave, int lane) {
    const int t   = (wave << 6) + lane;
    const int row = t >> 2;
    const int cb  = (t & 3) << 3;
    unsigned short* l0 = lds + (wave << 9);
    gl_lds16(g + (size_t)row * stride + cb, l0);
    gl_lds16(g + (size_t)(row + 64) * stride + cb, l0 + 2048);
}

// stage a 64x32 bf16 tile into LDS row-major [64][32]  (1 load/thread)
__device__ __forceinline__ void stage64x32(const unsigned short* g, int stride,
                                           unsigned short* lds, int wave, int lane) {
    const int t   = (wave << 6) + lane;
    const int row = t >> 2;
    const int cb  = (t & 3) << 3;
    gl_lds16(g + (size_t)row * stride + cb, lds + (wave << 9));
}

// 16 MFMAs, 128x128 tile, wave quadrant (wm,wn in {0,64})
__device__ __forceinline__ void mfma_step(const unsigned short* As, const unsigned short* Bs,
                                          int wm, int wn, int fr, int fo, floatx4 acc[4][4]) {
    short8 af[4], bf[4];
#pragma unroll
    for (int i = 0; i < 4; ++i) af[i] = *(const short8*)&As[(wm + i * 16 + fr) * 32 + fo];
#pragma unroll
    for (int j = 0; j < 4; ++j) bf[j] = *(const short8*)&Bs[(wn + j * 16 + fr) * 32 + fo];
#pragma unroll
    for (int i = 0; i < 4; ++i)
#pragma unroll
        for (int j = 0; j < 4; ++j)
            acc[i][j] = __builtin_amdgcn_mfma_f32_16x16x32_bf16(af[i], bf[j], acc[i][j], 0, 0, 0);
}

// 8 MFMAs + 2 ones-MFMAs (rowsum), 64x128 tile (wm in {0,32}, wn in {0,64})
__device__ __forceinline__ void mfma_step64d(const unsigned short* As, const unsigned short* Bs,
                                             int wm, int wn, int fr, int fo,
                                             floatx4 acc[2][4], floatx4 accd[2], short8 bones) {
    short8 af[2], bf[4];
#pragma unroll
    for (int i = 0; i < 2; ++i) af[i] = *(const short8*)&As[(wm + i * 16 + fr) * 32 + fo];
#pragma unroll
    for (int j = 0; j < 4; ++j) bf[j] = *(const short8*)&Bs[(wn + j * 16 + fr) * 32 + fo];
#pragma unroll
    for (int i = 0; i < 2; ++i) {
#pragma unroll
        for (int j = 0; j < 4; ++j)
            acc[i][j] = __builtin_amdgcn_mfma_f32_16x16x32_bf16(af[i], bf[j], acc[i][j], 0, 0, 0);
        accd[i] = __builtin_amdgcn_mfma_f32_16x16x32_bf16(af[i], bones, accd[i], 0, 0, 0);
    }
}

// 8 MFMAs, 64x128 tile (no rowsum)
__device__ __forceinline__ void mfma_step64(const unsigned short* As, const unsigned short* Bs,
                                            int wm, int wn, int fr, int fo, floatx4 acc[2][4]) {
    short8 af[2], bf[4];
#pragma unroll
    for (int i = 0; i < 2; ++i) af[i] = *(const short8*)&As[(wm + i * 16 + fr) * 32 + fo];
#pragma unroll
    for (int j = 0; j < 4; ++j) bf[j] = *(const short8*)&Bs[(wn + j * 16 + fr) * 32 + fo];
#pragma unroll
    for (int i = 0; i < 2; ++i)
#pragma unroll
        for (int j = 0; j < 4; ++j)
            acc[i][j] = __builtin_amdgcn_mfma_f32_16x16x32_bf16(af[i], bf[j], acc[i][j], 0, 0, 0);
}

// Double-buffered K-loop (round-7 proven), 128x128 tile.
__device__ __forceinline__ void gemm_loop_db(const unsigned short* Ag, int strideA,
                                             const unsigned short* Bg, int strideB, int Kk,
                                             unsigned short* As, unsigned short* Bs,
                                             int wave, int lane, int wm, int wn, int fr, int fo,
                                             floatx4 acc[4][4]) {
    __syncthreads();
    stage128x32(Ag, strideA, As, wave, lane);
    stage128x32(Bg, strideB, Bs, wave, lane);
    int buf = 0;
    for (int k0 = 32; k0 < Kk; k0 += 32) {
        __syncthreads();
        const int nb = buf ^ 1;
        stage128x32(Ag + k0, strideA, As + nb * TSZ, wave, lane);
        stage128x32(Bg + k0, strideB, Bs + nb * TSZ, wave, lane);
        mfma_step(As + buf * TSZ, Bs + buf * TSZ, wm, wn, fr, fo, acc);
        buf = nb;
    }
    __syncthreads();
    mfma_step(As + buf * TSZ, Bs + buf * TSZ, wm, wn, fr, fo, acc);
}

// Double-buffered K-loop, 64x128 tile, with in-register rowsum (den)
__device__ __forceinline__ void gemm_loop_db64d(const unsigned short* Ag, int strideA,
                                                const unsigned short* Bg, int strideB, int Kk,
                                                unsigned short* As, unsigned short* Bs,
                                                int wave, int lane, int wm, int wn, int fr, int fo,
                                                floatx4 acc[2][4], floatx4 accd[2], short8 bones) {
    __syncthreads();
    stage64x32(Ag, strideA, As, wave, lane);
    stage128x32(Bg, strideB, Bs, wave, lane);
    int buf = 0;
    for (int k0 = 32; k0 < Kk; k0 += 32) {
        __syncthreads();
        const int nb = buf ^ 1;
        stage64x32(Ag + k0, strideA, As + nb * TA64, wave, lane);
        stage128x32(Bg + k0, strideB, Bs + nb * TSZ, wave, lane);
        mfma_step64d(As + buf * TA64, Bs + buf * TSZ, wm, wn, fr, fo, acc, accd, bones);
        buf = nb;
    }
    __syncthreads();
    mfma_step64d(As + buf * TA64, Bs + buf * TSZ, wm, wn, fr, fo, acc, accd, bones);
}

// Double-buffered K-loop, 64x128 tile (plain)
__device__ __forceinline__ void gemm_loop_db64(const unsigned short* Ag, int strideA,
                                               const unsigned short* Bg, int strideB, int Kk,
                                               unsigned short* As, unsigned short* Bs,
                                               int wave, int lane, int wm, int wn, int fr, int fo,
                                               floatx4 acc[2][4]) {
    __syncthreads();
    stage64x32(Ag, strideA, As, wave, lane);
    stage128x32(Bg, strideB, Bs, wave, lane);
    int buf = 0;
    for (int k0 = 32; k0 < Kk; k0 += 32) {
        __syncthreads();
        const int nb = buf ^ 1;
        stage64x32(Ag + k0, strideA, As + nb * TA64, wave, lane);
        stage128x32(Bg + k0, strideB, Bs + nb * TSZ, wave, lane);
        mfma_step64(As + buf * TA64, Bs + buf * TSZ, wm, wn, fr, fo, acc);
        buf = nb;
    }
    __syncthreads();
    mfma_step64(As + buf * TA64, Bs + buf * TSZ, wm, wn, fr, fo, acc);
}

// ---------------- prep: cvt h + cvt 4 weights + transpose memory ----------------
__global__ __launch_bounds__(256) void prep(const float* __restrict__ h,
                                            const float* __restrict__ w_q, const float* __restrict__ w_k,
                                            const float* __restrict__ w_v, const float* __restrict__ w_o,
                                            const float* __restrict__ memory,
                                            unsigned short* __restrict__ h_b,
                                            unsigned short* __restrict__ wq_b, unsigned short* __restrict__ wk_b,
                                            unsigned short* __restrict__ wv_b, unsigned short* __restrict__ wo_b,
                                            unsigned short* __restrict__ memT)
{
    __shared__ unsigned short T[64][72];
    const int id = blockIdx.x, tid = threadIdx.x;
    if (id < 4096) {
        const size_t i = ((size_t)id * 256 + tid) * 4;
        float4 v = *(const float4*)(h + i);
        ushort4 o; o.x = f2bf(v.x); o.y = f2bf(v.y); o.z = f2bf(v.z); o.w = f2bf(v.w);
        *(ushort4*)(h_b + i) = o;
    } else if (id < 8192) {
        const int t = id - 4096, which = t >> 10;
        const float* in = (which == 0) ? w_q : (which == 1) ? w_k : (which == 2) ? w_v : w_o;
        unsigned short* out = (which == 0) ? wq_b : (which == 1) ? wk_b : (which == 2) ? wv_b : wo_b;
        const size_t i = ((size_t)(t & 1023) * 256 + tid) * 4;
        float4 v = *(const float4*)(in + i);
        ushort4 o; o.x = f2bf(v.x); o.y = f2bf(v.y); o.z = f2bf(v.z); o.w = f2bf(v.w);
        *(ushort4*)(out + i) = o;
    } else {
        const int t = id - 8192;
        const int d0 = (t >> 4) * 64, e0 = (t & 15) * 64;
        const int r = tid >> 4, c4 = (tid & 15) * 4;
        for (int rr = r; rr < 64; rr += 16) {
            float4 v = *(const float4*)(memory + (size_t)(d0 + rr) * D + e0 + c4);
            T[rr][c4 + 0] = f2bf(v.x); T[rr][c4 + 1] = f2bf(v.y);
            T[rr][c4 + 2] = f2bf(v.z); T[rr][c4 + 3] = f2bf(v.w);
        }
        __syncthreads();
        for (int rr = r; rr < 64; rr += 16) {
            ushort4 o;
            o.x = T[c4 + 0][rr]; o.y = T[c4 + 1][rr];
            o.z = T[c4 + 2][rr]; o.w = T[c4 + 3][rr];
            *(ushort4*)(memT + (size_t)(e0 + rr) * D + d0 + c4) = o;
        }
    }
}

// ---------------- fused q/k/v projections: 768 blocks, XCD-colocated ----------------
// Swizzle: xcd = id&7 (dispatch round-robin heuristic). All 8 n-tiles of one
// (sub,m) strip get ids congruent mod 8 -> same XCD -> A-tile L2-resident.
__global__ __launch_bounds__(256) void proj_fused(const unsigned short* __restrict__ h_b,
                                                  const unsigned short* __restrict__ wq,
                                                  const unsigned short* __restrict__ wk,
                                                  const unsigned short* __restrict__ wv,
                                                  unsigned short* __restrict__ sq,
                                                  unsigned short* __restrict__ sk,
                                                  unsigned short* __restrict__ v)
{
    __shared__ unsigned short As[2 * TSZ], Bs[2 * TSZ];
    const int id = blockIdx.x;
    const int x = id & 7, y = id >> 3;          // y: 0..95
    const int strip = x + 8 * (y % 12);         // 0..95 = sub*32 + m
    const int n     = y / 12;                   // 0..7
    const int sub = strip >> 5, m = strip & 31;
    const int m0 = m * 128, n0 = n * 128;
    const unsigned short* B = (sub == 0) ? wq : (sub == 1) ? wk : wv;
    unsigned short* C = (sub == 0) ? sq : (sub == 1) ? sk : v;

    const int tid = threadIdx.x, wave = tid >> 6, lane = tid & 63;
    const int wm = (wave >> 1) * 64, wn = (wave & 1) * 64;
    const int fr = lane & 15, fo = (lane >> 4) * 8;
    const int q4 = (lane >> 4) * 4;

    floatx4 acc[4][4] = {};
    gemm_loop_db(h_b + (size_t)m0 * D, D, B + (size_t)n0 * D, D, D,
                 As, Bs, wave, lane, wm, wn, fr, fo, acc);

#pragma unroll
    for (int i = 0; i < 4; ++i)
#pragma unroll
        for (int j = 0; j < 4; ++j) {
            const int col = n0 + wn + j * 16 + fr;
#pragma unroll
            for (int r = 0; r < 4; ++r) {
                const int row = m0 + wm + i * 16 + q4 + r;
                float val = acc[i][j][r];
                if (sub < 2) val = elu1(val);
                C[(size_t)row * D + col] = f2bf(val);
            }
        }
}

// ---------------- stage2: memgemm(256, swizzled) + scores(288) + v-transpose(1024) + rowscale(1024)
// Sbuf2 layout: [b][c][row 0..255][col 0..S) row-contiguous over all j slabs.
__global__ __launch_bounds__(256) void stage2(const unsigned short* __restrict__ sq,
                                              const unsigned short* __restrict__ sk,
                                              const unsigned short* __restrict__ memT,
                                              const unsigned short* __restrict__ v_b,
                                              const float* __restrict__ mnorm,
                                              const float* __restrict__ gate,
                                              unsigned short* __restrict__ combm,
                                              unsigned short* __restrict__ Sbuf2,
                                              unsigned short* __restrict__ vT,
                                              float* __restrict__ rowscale)
{
    __shared__ unsigned short As[2 * TSZ], Bs[2 * TSZ];
    const int id = blockIdx.x, tid = threadIdx.x;
    const int wave = tid >> 6, lane = tid & 63;
    const int wm = (wave >> 1) * 64, wn = (wave & 1) * 64;
    const int fr = lane & 15, fo = (lane >> 4) * 8;
    const int q4 = (lane >> 4) * 4;

    if (id < 256) {
        // combm = f2bf(sq @ memT^T); XCD swizzle: 8 n-tiles of one m-strip colocated
        const int x = id & 7, y = id >> 3;      // y: 0..31
        const int m0 = (x + 8 * (y & 3)) * 128; // strip 0..31
        const int n0 = (y >> 2) * 128;          // 0..7
        floatx4 acc[4][4] = {};
        gemm_loop_db(sq + (size_t)m0 * D, D, memT + (size_t)n0 * D, D, D,
                     As, Bs, wave, lane, wm, wn, fr, fo, acc);
#pragma unroll
        for (int i = 0; i < 4; ++i)
#pragma unroll
            for (int j = 0; j < 4; ++j) {
                const int col = n0 + wn + j * 16 + fr;
#pragma unroll
                for (int r = 0; r < 4; ++r)
                    combm[(size_t)(m0 + wm + i * 16 + q4 + r) * D + col] = f2bf(acc[i][j][r]);
            }
    } else if (id < 544) {
        // scores pair (c,j): rows of chunk c, col slab j*CH
        const int t = id - 256;
        const int b = t / 144, rem = t % 144;
        const int p = rem >> 2, tt = rem & 3;
        const int it = tt >> 1, jt = tt & 1;
        int c = 0;
        while ((c + 1) * (c + 2) / 2 <= p) ++c;
        const int j = p - c * (c + 1) / 2;
        unsigned short* Srow0 = Sbuf2 + (size_t)(b * NCH + c) * CH * S;

        if (j == c && jt > it) {  // fully above diagonal: zero-fill
            const int row = it * 128 + (tid >> 1);
            unsigned short* zp = Srow0 + (size_t)row * S + j * CH + jt * 128 + (tid & 1) * 64;
            uint4 z4 = make_uint4(0, 0, 0, 0);
#pragma unroll
            for (int i = 0; i < 8; ++i) *(uint4*)(zp + i * 8) = z4;
            return;
        }
        floatx4 acc[4][4] = {};
        gemm_loop_db(sq + ((size_t)b * S + (size_t)c * CH + it * 128) * D, D,
                     sk + ((size_t)b * S + (size_t)j * CH + jt * 128) * D, D, D,
                     As, Bs, wave, lane, wm, wn, fr, fo, acc);
        const bool diag = (j == c && it == jt);
#pragma unroll
        for (int i = 0; i < 4; ++i)
#pragma unroll
            for (int jj = 0; jj < 4; ++jj) {
                const int col = jt * 128 + wn + jj * 16 + fr;   // within slab
#pragma unroll
                for (int r = 0; r < 4; ++r) {
                    const int row = it * 128 + wm + i * 16 + q4 + r;
                    float val = acc[i][jj][r];
                    if (diag && col > row) val = 0.f;
                    Srow0[(size_t)row * S + j * CH + col] = f2bf(val);
                }
            }
    } else if (id < 1568) {
        // transpose v_b [b][s][d] -> vT [b][d][s], 64x64 tiles
        unsigned short (*T)[72] = (unsigned short(*)[72])As;
        const int t = id - 544;
        const int b = t >> 9, rem = t & 511;
        const int s0 = (rem >> 4) * 64, d0 = (rem & 15) * 64;
        const int r = tid >> 4, c4 = (tid & 15) * 4;
        const unsigned short* ip = v_b + (size_t)b * S * D;
        for (int rr = r; rr < 64; rr += 16) {
            ushort4 vv = *(const ushort4*)(ip + (size_t)(s0 + rr) * D + d0 + c4);
            T[rr][c4 + 0] = vv.x; T[rr][c4 + 1] = vv.y; T[rr][c4 + 2] = vv.z; T[rr][c4 + 3] = vv.w;
        }
        __syncthreads();
        unsigned short* op = vT + (size_t)b * D * S;
        for (int rr = r; rr < 64; rr += 16) {
            ushort4 o;
            o.x = T[c4 + 0][rr]; o.y = T[c4 + 1][rr];
            o.z = T[c4 + 2][rr]; o.w = T[c4 + 3][rr];
            *(ushort4*)(op + (size_t)(d0 + rr) * S + s0 + c4) = o;
        }
    } else {
        // rowscale[row] = g*active / clip(sq_row . mnorm)
        const int row = (id - 1568) * 4 + wave;
        const unsigned short* sr = sq + (size_t)row * D;
        float dot = 0.f, msum = 0.f;
        for (int d = lane; d < D; d += 64) {
            float mn = mnorm[d];
            dot += bf2f(sr[d]) * mn;
            msum += mn;
        }
        dot = wave_reduce(dot);
        msum = wave_reduce(msum);
        if (lane == 0) {
            const float g = sigmoidf_(gate[0]);
            const float active = (msum >= EPSF) ? 1.f : 0.f;
            rowscale[row] = g * active / fmaxf(dot, EPSF);
        }
    }
}

// ---------------- pv: combm = f2bf(combm*rowscale + (1-g)*(S@v)/den), den in-register ----------
// XCD swizzle: the 8 e-tiles of one (b,c,i0) group colocated (share the S-rows A-tile).
__global__ __launch_bounds__(256) void pv64(const unsigned short* __restrict__ Sbuf2,
                                            const unsigned short* __restrict__ vT,
                                            const float* __restrict__ rowscale,
                                            const float* __restrict__ gate,
                                            unsigned short* __restrict__ combm)
{
    __shared__ unsigned short As2[2 * TA64], Bs2[2 * TSZ];
    const int id = blockIdx.x, tid = threadIdx.x;
    const int wave = tid >> 6, lane = tid & 63;
    const int wm = (wave >> 1) * 32, wn = (wave & 1) * 64;
    const int fr = lane & 15, fo = (lane >> 4) * 8;
    const int q4 = (lane >> 4) * 4;

    const int x = id & 7, y = id >> 3;          // y: 0..63
    const int g_ = x + 8 * (y & 7);             // group 0..63 = (b, c-rev, i)
    const int e  = y >> 3;                      // 0..7
    const int b = g_ >> 5;
    const int rem = g_ & 31;
    const int c = (NCH - 1) - (rem >> 2);       // long-K groups first within XCD
    const int i0 = (rem & 3) * 64, e0 = e * 128;

    const short one_bf = (short)0x3F80;
    short8 bones = {one_bf, one_bf, one_bf, one_bf, one_bf, one_bf, one_bf, one_bf};

    floatx4 acc[2][4] = {};
    floatx4 accd[2] = {};
    gemm_loop_db64d(Sbuf2 + ((size_t)(b * NCH + c) * CH + i0) * S, S,
                    vT + (size_t)b * D * S + (size_t)e0 * S, S, (c + 1) * CH,
                    As2, Bs2, wave, lane, wm, wn, fr, fo, acc, accd, bones);

    const float g = sigmoidf_(gate[0]);
    const float wloc = 1.f - g;
#pragma unroll
    for (int i = 0; i < 2; ++i)
#pragma unroll
        for (int j = 0; j < 4; ++j) {
            const int col = e0 + wn + j * 16 + fr;
#pragma unroll
            for (int r = 0; r < 4; ++r) {
                const int li = i0 + wm + i * 16 + q4 + r;
                const int rg = b * S + c * CH + li;
                const float inv = wloc / fmaxf(accd[i][r], EPSF);
                const size_t idx = (size_t)rg * D + col;
                combm[idx] = f2bf(bf2f(combm[idx]) * rowscale[rg] + acc[i][j][r] * inv);
            }
        }
}

// ---------------- out-proj: out = combm @ wo^T (fp32), 512 blocks, XCD-colocated --------------
__global__ __launch_bounds__(256) void outproj64(const unsigned short* __restrict__ A,
                                                 const unsigned short* __restrict__ wo,
                                                 float* __restrict__ out)
{
    __shared__ unsigned short As2[2 * TA64], Bs2[2 * TSZ];
    const int id = blockIdx.x, tid = threadIdx.x;
    const int wave = tid >> 6, lane = tid & 63;
    const int wm = (wave >> 1) * 32, wn = (wave & 1) * 64;
    const int fr = lane & 15, fo = (lane >> 4) * 8;
    const int q4 = (lane >> 4) * 4;

    const int x = id & 7, y = id >> 3;          // y: 0..63
    const int m0 = (x + 8 * (y & 7)) * 64;      // strip 0..63 (64-row tiles)
    const int n0 = (y >> 3) * 128;              // 0..7

    floatx4 acc[2][4] = {};
    gemm_loop_db64(A + (size_t)m0 * D, D, wo + (size_t)n0 * D, D, D,
                   As2, Bs2, wave, lane, wm, wn, fr, fo, acc);

#pragma unroll
    for (int i = 0; i < 2; ++i)
#pragma unroll
        for (int j = 0; j < 4; ++j) {
            const int col = n0 + wn + j * 16 + fr;
#pragma unroll
            for (int r = 0; r < 4; ++r)
                out[(size_t)(m0 + wm + i * 16 + q4 + r) * D + col] = acc[i][j][r];
        }
}

extern "C" void kernel_launch(void* const* d_in, const int* in_sizes, int n_in,
                              void* d_out, int out_size, void* d_ws, size_t ws_size,
                              hipStream_t stream)
{
    const float* h      = (const float*)d_in[0];
    const float* w_q    = (const float*)d_in[1];
    const float* w_k    = (const float*)d_in[2];
    const float* w_v    = (const float*)d_in[3];
    const float* w_o    = (const float*)d_in[4];
    const float* gate   = (const float*)d_in[5];
    const float* memory = (const float*)d_in[6];
    const float* mnorm  = (const float*)d_in[7];
    float* out = (float*)d_out;

    // ---- workspace (~75 MB), no aliasing ----
    unsigned short* h_b   = (unsigned short*)d_ws;               // M*D (8 MB)
    unsigned short* wq_b  = h_b + (size_t)M * D;                 // D*D
    unsigned short* wk_b  = wq_b + (size_t)D * D;                // D*D
    unsigned short* wv_b  = wk_b + (size_t)D * D;                // D*D
    unsigned short* wo_b  = wv_b + (size_t)D * D;                // D*D
    unsigned short* memT  = wo_b + (size_t)D * D;                // D*D (2 MB)
    unsigned short* sq_b  = memT + (size_t)D * D;                // M*D (8 MB)
    unsigned short* sk_b  = sq_b + (size_t)M * D;                // M*D (8 MB)
    unsigned short* v_b   = sk_b + (size_t)M * D;                // M*D (8 MB)
    unsigned short* vT    = v_b + (size_t)M * D;                 // M*D (8 MB)
    unsigned short* Sbuf2 = vT + (size_t)M * D;                  // Bv*NCH*CH*S (16.8 MB)
    unsigned short* combm = Sbuf2 + (size_t)Bv * NCH * CH * S;   // M*D (8 MB)
    float* rowscale = (float*)(combm + (size_t)M * D);           // M fp32

    dim3 blk(256);

    prep<<<8448, blk, 0, stream>>>(h, w_q, w_k, w_v, w_o, memory,
                                   h_b, wq_b, wk_b, wv_b, wo_b, memT);
    proj_fused<<<768, blk, 0, stream>>>(h_b, wq_b, wk_b, wv_b, sq_b, sk_b, v_b);
    stage2<<<2592, blk, 0, stream>>>(sq_b, sk_b, memT, v_b, mnorm, gate,
                                     combm, Sbuf2, vT, rowscale);
    pv64<<<512, blk, 0, stream>>>(Sbuf2, vT, rowscale, gate, combm);
    outproj64<<<512, blk, 0, stream>>>(combm, wo_b, out);
}